// Round 2
// baseline (665.951 us; speedup 1.0000x reference)
//
#include <hip/hip_runtime.h>
#include <stdint.h>

// ---------------------------------------------------------------------------
// LSH attention, B=4 S=2048 E=1024, fp32 in/out.
// All GEMMs are bf16 MFMA with "3K split packing" for ~fp32 accuracy:
//   x = hi + lo (hi=bf16(x), lo=bf16(x-hi))
//   A packed along K as [hi | hi | lo], B packed as [hi | lo | hi]
//   => standard bf16 dot over 3K computes hi*hi + hi*lo + lo*hi  (err ~1e-5)
// ---------------------------------------------------------------------------

#define B_ 4
#define S_ 2048
#define E_ 1024
#define K3 3072   // 3*E : packed K for proj + scores GEMMs
#define K6 6144   // 3*S : packed K for PV GEMM

#define BM 128
#define BN 128
#define BK 64

// workspace byte offsets (total need: 253,755,392 bytes)
#define OFF_HHAT 0ULL            // [8192][3072] bf16 = 50,331,648
#define OFF_WHAT 50331648ULL     // [3][1024][3072] bf16 = 18,874,368
#define OFF_QHAT 69206016ULL     // [8192][3072] bf16 (pattern hi,hi,lo)
#define OFF_KHAT 119537664ULL    // [8192][3072] bf16 (pattern hi,lo,hi)
#define OFF_VT   169869312ULL    // [4][1024][6144] bf16 (pattern hi,lo,hi over t)
#define OFF_VHI  220200960ULL    // [8192][1024] bf16
#define OFF_VLO  236978176ULL    // [8192][1024] bf16
#define OFF_SC   0ULL            // scores f32 [4][2048][2048] = 67,108,864 (reuses Hhat+What)
#define OFF_PHAT 69206016ULL     // [4][2048][6144] bf16 = 100,663,296 (reuses Qhat+Khat)

typedef __attribute__((ext_vector_type(8))) short bf16x8;
typedef __attribute__((ext_vector_type(4))) float f32x4;

__device__ __forceinline__ uint16_t f2bf(float x) {
    uint32_t u = __float_as_uint(x);
    uint32_t r = (u + 0x7fffu + ((u >> 16) & 1u)) >> 16;   // RNE
    return (uint16_t)r;
}
__device__ __forceinline__ float bf2f(uint16_t b) {
    return __uint_as_float(((uint32_t)b) << 16);
}

// ---------------------------------------------------------------------------
// pack: h -> Hhat [hi,hi,lo]; Wq/Wk/Wv -> What [hi,lo,hi]
// ---------------------------------------------------------------------------
__global__ void pack_inputs(const float* __restrict__ h,
                            const float* __restrict__ Wq, const float* __restrict__ Wk,
                            const float* __restrict__ Wv,
                            uint16_t* __restrict__ Hhat, uint16_t* __restrict__ What)
{
    int r = blockIdx.x;                 // 0..11263 : 8192 h-rows then 3*1024 W-rows
    const float* src;
    uint16_t* dst;
    int pat;
    if (r < 8192) {
        src = h + (size_t)r * E_;
        dst = Hhat + (size_t)r * K3;
        pat = 0;                        // [hi,hi,lo]
    } else {
        int w = r - 8192;
        int wz = w >> 10, wr = w & 1023;
        const float* W = (wz == 0) ? Wq : (wz == 1) ? Wk : Wv;
        src = W + (size_t)wr * E_;
        dst = What + ((size_t)wz * E_ + wr) * K3;
        pat = 1;                        // [hi,lo,hi]
    }
    int c = threadIdx.x * 4;
    float4 x = *(const float4*)(src + c);
    float xs[4] = {x.x, x.y, x.z, x.w};
    uint16_t h4[4], l4[4];
#pragma unroll
    for (int i = 0; i < 4; ++i) {
        h4[i] = f2bf(xs[i]);
        l4[i] = f2bf(xs[i] - bf2f(h4[i]));
    }
    ushort4 hv = make_ushort4(h4[0], h4[1], h4[2], h4[3]);
    ushort4 lv = make_ushort4(l4[0], l4[1], l4[2], l4[3]);
    *(ushort4*)(dst + c) = hv;
    if (pat == 0) {
        *(ushort4*)(dst + E_ + c) = hv;
        *(ushort4*)(dst + 2 * E_ + c) = lv;
    } else {
        *(ushort4*)(dst + E_ + c) = lv;
        *(ushort4*)(dst + 2 * E_ + c) = hv;
    }
}

// ---------------------------------------------------------------------------
// GEMM core: C[128x128] tile, NT (both operands K-major), bf16 16x16x32 MFMA,
// global_load_lds width-16 staging, 2-phase (m97 structure).
// ---------------------------------------------------------------------------
__device__ __forceinline__ void gemm_core(const uint16_t* __restrict__ A,
                                          const uint16_t* __restrict__ Bm,
                                          int K, int tileM, int tileN,
                                          uint16_t* As, uint16_t* Bs,
                                          f32x4 acc[4][4])
{
    const int tid  = threadIdx.x;
    const int lane = tid & 63;
    const int wave = tid >> 6;
    const int wr = wave >> 1, wc = wave & 1;

    // staging: each lane loads 16B; LDS dest = wave-uniform base + lane*16
    const int srow = (wave << 3) + (lane >> 3);     // 8 lanes per 128B row
    const int scol = (lane & 7) << 3;               // elem offset within row
    const uint16_t* gA = A  + (size_t)(tileM + srow) * K + scol;
    const uint16_t* gB = Bm + (size_t)(tileN + srow) * K + scol;

    for (int k0 = 0; k0 < K; k0 += BK) {
#pragma unroll
        for (int it = 0; it < 4; ++it) {
            __builtin_amdgcn_global_load_lds(
                (const __attribute__((address_space(1))) uint32_t*)(gA + (size_t)(it * 32) * K + k0),
                (__attribute__((address_space(3))) uint32_t*)(As + (it * 4 + wave) * 512),
                16, 0, 0);
        }
#pragma unroll
        for (int it = 0; it < 4; ++it) {
            __builtin_amdgcn_global_load_lds(
                (const __attribute__((address_space(1))) uint32_t*)(gB + (size_t)(it * 32) * K + k0),
                (__attribute__((address_space(3))) uint32_t*)(Bs + (it * 4 + wave) * 512),
                16, 0, 0);
        }
        __syncthreads();   // drains vmcnt before any wave reads LDS
#pragma unroll
        for (int ks = 0; ks < 2; ++ks) {
            bf16x8 af[4], bfr[4];
#pragma unroll
            for (int i = 0; i < 4; ++i)
                af[i] = *(const bf16x8*)&As[(wr * 64 + i * 16 + (lane & 15)) * BK + ks * 32 + (lane >> 4) * 8];
#pragma unroll
            for (int j = 0; j < 4; ++j)
                bfr[j] = *(const bf16x8*)&Bs[(wc * 64 + j * 16 + (lane & 15)) * BK + ks * 32 + (lane >> 4) * 8];
#pragma unroll
            for (int i = 0; i < 4; ++i)
#pragma unroll
                for (int j = 0; j < 4; ++j)
                    acc[i][j] = __builtin_amdgcn_mfma_f32_16x16x32_bf16(af[i], bfr[j], acc[i][j], 0, 0, 0);
        }
        __syncthreads();
    }
}

// ---------------------------------------------------------------------------
// QKV projection: A=Hhat[8192,3072], B=What[z][1024,3072], z=blockIdx.z
// epilogue: +bias, split to Qhat [hi,hi,lo] / Khat [hi,lo,hi] / Vhi+Vlo planar
// ---------------------------------------------------------------------------
__global__ __launch_bounds__(256) void gemm_proj(
    const uint16_t* __restrict__ Hhat, const uint16_t* __restrict__ What,
    const float* __restrict__ bq, const float* __restrict__ bk, const float* __restrict__ bv,
    uint16_t* __restrict__ Qhat, uint16_t* __restrict__ Khat,
    uint16_t* __restrict__ Vhi, uint16_t* __restrict__ Vlo)
{
    __shared__ __align__(16) uint16_t As[BM * BK];
    __shared__ __align__(16) uint16_t Bs[BN * BK];
    f32x4 acc[4][4];
#pragma unroll
    for (int i = 0; i < 4; ++i)
#pragma unroll
        for (int j = 0; j < 4; ++j) acc[i][j] = (f32x4){0.f, 0.f, 0.f, 0.f};

    const int z = blockIdx.z;
    const int tileM = blockIdx.y * BM, tileN = blockIdx.x * BN;
    const uint16_t* Bmat = What + (size_t)z * E_ * K3;
    gemm_core(Hhat, Bmat, K3, tileM, tileN, As, Bs, acc);

    const float* bias = (z == 0) ? bq : (z == 1) ? bk : bv;
    const int lane = threadIdx.x & 63, wave = threadIdx.x >> 6;
    const int wr = wave >> 1, wc = wave & 1;
#pragma unroll
    for (int i = 0; i < 4; ++i) {
#pragma unroll
        for (int j = 0; j < 4; ++j) {
            int col = tileN + wc * 64 + j * 16 + (lane & 15);
            float bc = bias[col];
#pragma unroll
            for (int r = 0; r < 4; ++r) {
                int row = tileM + wr * 64 + i * 16 + (lane >> 4) * 4 + r;
                float v = acc[i][j][r] + bc;
                uint16_t hi = f2bf(v);
                uint16_t lo = f2bf(v - bf2f(hi));
                if (z == 0) {
                    size_t base = (size_t)row * K3;
                    Qhat[base + col] = hi; Qhat[base + E_ + col] = hi; Qhat[base + 2 * E_ + col] = lo;
                } else if (z == 1) {
                    size_t base = (size_t)row * K3;
                    Khat[base + col] = hi; Khat[base + E_ + col] = lo; Khat[base + 2 * E_ + col] = hi;
                } else {
                    size_t base = (size_t)row * E_ + col;
                    Vhi[base] = hi; Vlo[base] = lo;
                }
            }
        }
    }
}

// ---------------------------------------------------------------------------
// generic GEMM with f32 output: C[b] = scale * A[b] * B[b]^T
// used for scores (K=3072, N=2048) and PV (K=6144, N=1024)
// ---------------------------------------------------------------------------
__global__ __launch_bounds__(256) void gemm_f32(
    const uint16_t* __restrict__ A, const uint16_t* __restrict__ Bm, float* __restrict__ C,
    int K, int N, float scale, long sA, long sB, long sC)
{
    __shared__ __align__(16) uint16_t As[BM * BK];
    __shared__ __align__(16) uint16_t Bs[BN * BK];
    f32x4 acc[4][4];
#pragma unroll
    for (int i = 0; i < 4; ++i)
#pragma unroll
        for (int j = 0; j < 4; ++j) acc[i][j] = (f32x4){0.f, 0.f, 0.f, 0.f};

    const int bz = blockIdx.z;
    const uint16_t* Ab = A  + (size_t)bz * sA;
    const uint16_t* Bb = Bm + (size_t)bz * sB;
    float* Cb = C + (size_t)bz * sC;
    const int tileM = blockIdx.y * BM, tileN = blockIdx.x * BN;
    gemm_core(Ab, Bb, K, tileM, tileN, As, Bs, acc);

    const int lane = threadIdx.x & 63, wave = threadIdx.x >> 6;
    const int wr = wave >> 1, wc = wave & 1;
#pragma unroll
    for (int i = 0; i < 4; ++i)
#pragma unroll
        for (int j = 0; j < 4; ++j) {
            int col = tileN + wc * 64 + j * 16 + (lane & 15);
#pragma unroll
            for (int r = 0; r < 4; ++r) {
                int row = tileM + wr * 64 + i * 16 + (lane >> 4) * 4 + r;
                Cb[(size_t)row * N + col] = acc[i][j][r] * scale;
            }
        }
}

// ---------------------------------------------------------------------------
// V transpose: Vhi/Vlo [b][t][e] -> Vt [b][e][3T] pattern [hi | lo | hi]
// ---------------------------------------------------------------------------
__global__ void transpose_v(const uint16_t* __restrict__ Vhi, const uint16_t* __restrict__ Vlo,
                            uint16_t* __restrict__ Vt)
{
    __shared__ uint16_t sh[32][33];
    __shared__ uint16_t sl[32][33];
    const int b = blockIdx.z;
    const int t0 = blockIdx.x * 32, e0 = blockIdx.y * 32;
    const int tx = threadIdx.x & 31, ty = threadIdx.x >> 5;   // 8 rows at a time
    for (int r = ty; r < 32; r += 8) {
        size_t src = ((size_t)b * S_ + t0 + r) * E_ + e0 + tx;
        sh[r][tx] = Vhi[src];
        sl[r][tx] = Vlo[src];
    }
    __syncthreads();
    for (int r = ty; r < 32; r += 8) {
        size_t base = ((size_t)b * E_ + e0 + r) * (size_t)K6;
        uint16_t h = sh[tx][r], l = sl[tx][r];
        Vt[base + t0 + tx] = h;
        Vt[base + S_ + t0 + tx] = l;
        Vt[base + 2 * S_ + t0 + tx] = h;
    }
}

// ---------------------------------------------------------------------------
// masked softmax over one score row + split-pack P: Phat [hi | hi | lo] over t
// ---------------------------------------------------------------------------
__global__ __launch_bounds__(256) void softmax_split(const float* __restrict__ scores,
                                                     const int* __restrict__ buckets,
                                                     uint16_t* __restrict__ Phat)
{
    const int s = blockIdx.x, b = blockIdx.y;
    const float* row = scores + ((size_t)b * S_ + s) * S_;
    const int* brow = buckets + b * S_;
    const int myb = brow[s];
    const int tid = threadIdx.x;
    const int lane = tid & 63, wave = tid >> 6;

    float vals[8];
    float m = -1e30f;
#pragma unroll
    for (int i = 0; i < 8; ++i) {
        int t = tid + i * 256;
        float x = row[t];
        x = (brow[t] == myb) ? x : -1e30f;   // diagonal always valid -> m stays sane
        vals[i] = x;
        m = fmaxf(m, x);
    }
#pragma unroll
    for (int off = 32; off > 0; off >>= 1) m = fmaxf(m, __shfl_xor(m, off));
    __shared__ float red[8];
    if (lane == 0) red[wave] = m;
    __syncthreads();
    m = fmaxf(fmaxf(red[0], red[1]), fmaxf(red[2], red[3]));

    float sum = 0.f;
#pragma unroll
    for (int i = 0; i < 8; ++i) {
        float p = __expf(vals[i] - m);       // exp(-1e30 - m) == 0
        vals[i] = p;
        sum += p;
    }
#pragma unroll
    for (int off = 32; off > 0; off >>= 1) sum += __shfl_xor(sum, off);
    if (lane == 0) red[4 + wave] = sum;
    __syncthreads();
    sum = red[4] + red[5] + red[6] + red[7];
    float inv = 1.f / sum;

    size_t base = ((size_t)b * S_ + s) * (size_t)K6;
#pragma unroll
    for (int i = 0; i < 8; ++i) {
        int t = tid + i * 256;
        float p = vals[i] * inv;
        uint16_t hi = f2bf(p);
        uint16_t lo = f2bf(p - bf2f(hi));
        Phat[base + t] = hi;
        Phat[base + S_ + t] = hi;
        Phat[base + 2 * S_ + t] = lo;
    }
}

// ---------------------------------------------------------------------------
extern "C" void kernel_launch(void* const* d_in, const int* in_sizes, int n_in,
                              void* d_out, int out_size, void* d_ws, size_t ws_size,
                              hipStream_t stream)
{
    const float* h  = (const float*)d_in[0];
    const int*   hb = (const int*)d_in[1];
    const float* Wq = (const float*)d_in[2];
    const float* bq = (const float*)d_in[3];
    const float* Wk = (const float*)d_in[4];
    const float* bk = (const float*)d_in[5];
    const float* Wv = (const float*)d_in[6];
    const float* bv = (const float*)d_in[7];
    float* out = (float*)d_out;
    uint8_t* ws = (uint8_t*)d_ws;

    uint16_t* Hhat = (uint16_t*)(ws + OFF_HHAT);
    uint16_t* What = (uint16_t*)(ws + OFF_WHAT);
    uint16_t* Qhat = (uint16_t*)(ws + OFF_QHAT);
    uint16_t* Khat = (uint16_t*)(ws + OFF_KHAT);
    uint16_t* Vt   = (uint16_t*)(ws + OFF_VT);
    uint16_t* Vhi  = (uint16_t*)(ws + OFF_VHI);
    uint16_t* Vlo  = (uint16_t*)(ws + OFF_VLO);
    float*    sc   = (float*)(ws + OFF_SC);     // overlays Hhat+What (dead by then)
    uint16_t* Phat = (uint16_t*)(ws + OFF_PHAT);// overlays Qhat+Khat (dead by then)

    // 1) split-pack inputs
    pack_inputs<<<dim3(11264), 256, 0, stream>>>(h, Wq, Wk, Wv, Hhat, What);
    // 2) fused QKV projection (z: 0=Q,1=K,2=V)
    gemm_proj<<<dim3(8, 64, 3), 256, 0, stream>>>(Hhat, What, bq, bk, bv, Qhat, Khat, Vhi, Vlo);
    // 3) V -> [e][3t] layout for PV NT-GEMM
    transpose_v<<<dim3(64, 32, 4), 256, 0, stream>>>(Vhi, Vlo, Vt);
    // 4) scores = Q K^T / 32
    gemm_f32<<<dim3(16, 16, 4), 256, 0, stream>>>(Qhat, Khat, sc, K3, S_, 1.0f / 32.0f,
                                                  (long)S_ * K3, (long)S_ * K3, (long)S_ * S_);
    // 5) bucket-masked softmax + split-pack P
    softmax_split<<<dim3(S_, B_), 256, 0, stream>>>(sc, hb, Phat);
    // 6) context = P V
    gemm_f32<<<dim3(8, 16, 4), 256, 0, stream>>>(Phat, Vt, out, K6, E_, 1.0f,
                                                 (long)S_ * K6, (long)E_ * K6, (long)S_ * E_);
}

// Round 8
// 519.326 us; speedup vs baseline: 1.2823x; 1.2823x over previous
//
#include <hip/hip_runtime.h>
#include <stdint.h>

// ---------------------------------------------------------------------------
// LSH attention, B=4 S=2048 E=1024, fp32 in/out.
// GEMMs: bf16 MFMA with "3K split packing" (x = hi+lo; A:[hi,hi,lo] B:[hi,lo,hi]
// along K => hi*hi + hi*lo + lo*hi, err ~1e-5). Numerics identical to the
// round-2 passing kernel (absmax 9.77e-4).
//
// 256-wide-tile 4-phase pipelined GEMM core:
//  - 512 thr / 8 waves (2M x 4N), BK=64, LDS halves [khalf][rows][32] linear
//  - counted s_waitcnt vmcnt(GATE) gates (never 0); halves of tile t+1 issued
//    one-per-phase during tile t; dummy-wrap staging keeps counts uniform;
//    post-loop vmcnt(0) drain before epilogue/endpgm (hardening, r3)
//  - T2 st-swizzle: write side pre-swizzles the GLOBAL granule, read side
//    XORs byte bit5 with bit9 (same involution; verified elementwise)
//  - T5 setprio around MFMA cluster; T1 bijective XCD swizzle on blockIdx
// ---------------------------------------------------------------------------

#define B_ 4
#define S_ 2048
#define E_ 1024
#define K3 3072   // 3*E : packed K for proj + scores GEMMs
#define K6 6144   // 3*S : packed K for PV GEMM

// workspace byte offsets (total need: 253,755,392 bytes)
#define OFF_HHAT 0ULL            // [8192][3072] bf16
#define OFF_WHAT 50331648ULL     // [3][1024][3072] bf16
#define OFF_QHAT 69206016ULL     // [8192][3072] bf16 (hi,hi,lo)
#define OFF_KHAT 119537664ULL    // [8192][3072] bf16 (hi,lo,hi)
#define OFF_VT   169869312ULL    // [4][1024][6144] bf16 (hi,lo,hi over t)
#define OFF_VHI  220200960ULL    // [8192][1024] bf16
#define OFF_VLO  236978176ULL    // [8192][1024] bf16
#define OFF_SC   0ULL            // scores f32 [4][2048][2048] (reuses Hhat+What)
#define OFF_PHAT 69206016ULL     // [4][2048][6144] bf16 (reuses Qhat+Khat)

typedef __attribute__((ext_vector_type(8))) short bf16x8;
typedef __attribute__((ext_vector_type(4))) float f32x4;

__device__ __forceinline__ uint16_t f2bf(float x) {
    uint32_t u = __float_as_uint(x);
    uint32_t r = (u + 0x7fffu + ((u >> 16) & 1u)) >> 16;   // RNE
    return (uint16_t)r;
}
__device__ __forceinline__ float bf2f(uint16_t b) {
    return __uint_as_float(((uint32_t)b) << 16);
}

// ---------------------------------------------------------------------------
// pack: h -> Hhat [hi,hi,lo]; Wq/Wk/Wv -> What [hi,lo,hi]
// ---------------------------------------------------------------------------
__global__ void pack_inputs(const float* __restrict__ h,
                            const float* __restrict__ Wq, const float* __restrict__ Wk,
                            const float* __restrict__ Wv,
                            uint16_t* __restrict__ Hhat, uint16_t* __restrict__ What)
{
    int r = blockIdx.x;                 // 0..11263 : 8192 h-rows then 3*1024 W-rows
    const float* src;
    uint16_t* dst;
    int pat;
    if (r < 8192) {
        src = h + (size_t)r * E_;
        dst = Hhat + (size_t)r * K3;
        pat = 0;
    } else {
        int w = r - 8192;
        int wz = w >> 10, wr = w & 1023;
        const float* W = (wz == 0) ? Wq : (wz == 1) ? Wk : Wv;
        src = W + (size_t)wr * E_;
        dst = What + ((size_t)wz * E_ + wr) * K3;
        pat = 1;
    }
    int c = threadIdx.x * 4;
    float4 x = *(const float4*)(src + c);
    float xs[4] = {x.x, x.y, x.z, x.w};
    uint16_t h4[4], l4[4];
#pragma unroll
    for (int i = 0; i < 4; ++i) {
        h4[i] = f2bf(xs[i]);
        l4[i] = f2bf(xs[i] - bf2f(h4[i]));
    }
    ushort4 hv = make_ushort4(h4[0], h4[1], h4[2], h4[3]);
    ushort4 lv = make_ushort4(l4[0], l4[1], l4[2], l4[3]);
    *(ushort4*)(dst + c) = hv;
    if (pat == 0) {
        *(ushort4*)(dst + E_ + c) = hv;
        *(ushort4*)(dst + 2 * E_ + c) = lv;
    } else {
        *(ushort4*)(dst + E_ + c) = lv;
        *(ushort4*)(dst + 2 * E_ + c) = hv;
    }
}

// ---------------------------------------------------------------------------
// Pipelined GEMM core. Tile BMT x 256, BK=64, NT (both K-major), 512 threads.
// LDS buf layout (per double-buffer slot, all 1024-aligned):
//   A: [khalf][BMT rows][32 cols] bf16   (2 * BMT*64 bytes)
//   B: [khalf][256 rows][32 cols] bf16   (2 * 16384 bytes)
// Phase p = (khalf = p>>1, mhalf = p&1). Stage order per tile: Ak0,Bk0,Ak1,Bk1
// (one half per phase, for tile t+1, into the other buffer).
// Gates: vmcnt(GATE) before barrier at p==1 (cur tile k1 halves) and p==3
// (next tile k0 halves). GATE = CW_A + 2 calls/wave. Last tile stages tile 0
// (dummy) so the outstanding-count arithmetic stays uniform.
// ---------------------------------------------------------------------------
template<int BMT>
__device__ __forceinline__ void gemm_core256(const uint16_t* __restrict__ A,
                                             const uint16_t* __restrict__ Bm,
                                             int K, int tileM, int tileN,
                                             uint8_t* smem, f32x4 (*acc)[4])
{
    constexpr int MF     = BMT / 32;     // m-frags per wave
    constexpr int MF2    = MF / 2;       // m-frags per phase
    constexpr int A_HALF = BMT * 64;     // bytes per A k-half
    constexpr int BBASE  = 2 * A_HALF;
    constexpr int BUFSZ  = 2 * A_HALF + 32768;
    constexpr int CW_A   = BMT / 128;    // A gload_lds calls per wave per half
    constexpr int GATE   = CW_A + 2;

    const int tid  = threadIdx.x;
    const int lane = tid & 63;
    const int wave = tid >> 6;           // 0..7
    const int waveM = wave >> 2;         // 0..1
    const int waveN = wave & 3;          // 0..3
    const int nT = K >> 6;

    const int srow = lane >> 2;                               // row within 16-row chunk
    const int g8   = ((lane & 3) ^ ((lane >> 5) << 1)) * 8;   // pre-swizzled src granule

    auto stageA = [&](uint8_t* bufW, int t, int h) {
#pragma unroll
        for (int cc = 0; cc < CW_A; ++cc) {
            const int c = wave * CW_A + cc;
            const uint16_t* src = A + (size_t)(tileM + c * 16 + srow) * K + t * 64 + h * 32 + g8;
            uint8_t* dst = bufW + h * A_HALF + c * 1024;
            __builtin_amdgcn_global_load_lds(
                (const __attribute__((address_space(1))) uint32_t*)src,
                (__attribute__((address_space(3))) uint32_t*)dst, 16, 0, 0);
        }
    };
    auto stageB = [&](uint8_t* bufW, int t, int h) {
#pragma unroll
        for (int cc = 0; cc < 2; ++cc) {
            const int c = wave * 2 + cc;
            const uint16_t* src = Bm + (size_t)(tileN + c * 16 + srow) * K + t * 64 + h * 32 + g8;
            uint8_t* dst = bufW + BBASE + h * 16384 + c * 1024;
            __builtin_amdgcn_global_load_lds(
                (const __attribute__((address_space(1))) uint32_t*)src,
                (__attribute__((address_space(3))) uint32_t*)dst, 16, 0, 0);
        }
    };

    // prologue: stage tile 0 fully; gate its k0 halves
    stageA(smem, 0, 0); stageB(smem, 0, 0); stageA(smem, 0, 1); stageB(smem, 0, 1);
    asm volatile("s_waitcnt vmcnt(%0)" :: "i"(GATE) : "memory");
    __builtin_amdgcn_s_barrier();

    for (int t = 0; t < nT; ++t) {
        uint8_t* bufR = smem + (t & 1) * BUFSZ;
        uint8_t* bufW = smem + ((t & 1) ^ 1) * BUFSZ;
        const int tn = (t + 1 == nT) ? 0 : t + 1;   // dummy wrap on last tile
        bf16x8 bfrag[4];
#pragma unroll
        for (int p = 0; p < 4; ++p) {
            const int kh = p >> 1, mh = p & 1;
            if (mh == 0) {
#pragma unroll
                for (int n = 0; n < 4; ++n) {
                    int off = BBASE + kh * 16384 +
                              (waveN * 64 + n * 16 + (lane & 15)) * 64 + (lane >> 4) * 16;
                    off ^= ((off >> 9) & 1) << 5;
                    bfrag[n] = *(const bf16x8*)(bufR + off);
                }
            }
            bf16x8 afrag[MF2];
#pragma unroll
            for (int i = 0; i < MF2; ++i) {
                int off = kh * A_HALF +
                          (waveM * (BMT / 2) + (mh * MF2 + i) * 16 + (lane & 15)) * 64 +
                          (lane >> 4) * 16;
                off ^= ((off >> 9) & 1) << 5;
                afrag[i] = *(const bf16x8*)(bufR + off);
            }
            if (p == 0)      stageA(bufW, tn, 0);
            else if (p == 1) stageB(bufW, tn, 0);
            else if (p == 2) stageA(bufW, tn, 1);
            else             stageB(bufW, tn, 1);
            if (p == 1 || p == 3)
                asm volatile("s_waitcnt vmcnt(%0)" :: "i"(GATE) : "memory");
            __builtin_amdgcn_s_barrier();
            __builtin_amdgcn_s_setprio(1);
#pragma unroll
            for (int i = 0; i < MF2; ++i)
#pragma unroll
                for (int n = 0; n < 4; ++n)
                    acc[mh * MF2 + i][n] = __builtin_amdgcn_mfma_f32_16x16x32_bf16(
                        afrag[i], bfrag[n], acc[mh * MF2 + i][n], 0, 0, 0);
            __builtin_amdgcn_s_setprio(0);
            __builtin_amdgcn_s_barrier();
        }
    }
    // drain dummy-wrap stages before epilogue / endpgm (hardening)
    asm volatile("s_waitcnt vmcnt(0)" ::: "memory");
    __builtin_amdgcn_s_barrier();
}

// ---------------------------------------------------------------------------
// QKV projection: A=Hhat[8192,3072], B=What[z][1024,3072]; 256x256 tiles.
// grid 384 = 4(N) * 32(M) * 3(z), bijectively XCD-swizzled (384 = 48*8).
// ---------------------------------------------------------------------------
__global__ __launch_bounds__(512, 2) void gemm_proj2(
    const uint16_t* __restrict__ Hhat, const uint16_t* __restrict__ What,
    const float* __restrict__ bq, const float* __restrict__ bk, const float* __restrict__ bv,
    uint16_t* __restrict__ Qhat, uint16_t* __restrict__ Khat,
    uint16_t* __restrict__ Vhi, uint16_t* __restrict__ Vlo)
{
    __shared__ __align__(16) uint8_t smem[131072];
    const int f = blockIdx.x;
    const int swz = (f & 7) * 48 + (f >> 3);      // T1: 384 = 8*48
    const int z = swz >> 7;                       // /128
    const int rm = swz & 127;
    const int tileM = (rm >> 2) * 256, tileN = (rm & 3) * 256;

    f32x4 acc[8][4];
#pragma unroll
    for (int i = 0; i < 8; ++i)
#pragma unroll
        for (int j = 0; j < 4; ++j) acc[i][j] = (f32x4){0.f, 0.f, 0.f, 0.f};

    gemm_core256<256>(Hhat, What + (size_t)z * E_ * K3, K3, tileM, tileN, smem, acc);

    const float* bias = (z == 0) ? bq : (z == 1) ? bk : bv;
    const int lane = threadIdx.x & 63, wave = threadIdx.x >> 6;
    const int waveM = wave >> 2, waveN = wave & 3;
#pragma unroll
    for (int i = 0; i < 8; ++i) {
#pragma unroll
        for (int j = 0; j < 4; ++j) {
            int col = tileN + waveN * 64 + j * 16 + (lane & 15);
            float bc = bias[col];
#pragma unroll
            for (int r = 0; r < 4; ++r) {
                int row = tileM + waveM * 128 + i * 16 + (lane >> 4) * 4 + r;
                float v = acc[i][j][r] + bc;
                uint16_t hi = f2bf(v);
                uint16_t lo = f2bf(v - bf2f(hi));
                if (z == 0) {
                    size_t base = (size_t)row * K3;
                    Qhat[base + col] = hi; Qhat[base + E_ + col] = hi; Qhat[base + 2 * E_ + col] = lo;
                } else if (z == 1) {
                    size_t base = (size_t)row * K3;
                    Khat[base + col] = hi; Khat[base + E_ + col] = lo; Khat[base + 2 * E_ + col] = hi;
                } else {
                    size_t base = (size_t)row * E_ + col;
                    Vhi[base] = hi; Vlo[base] = lo;
                }
            }
        }
    }
}

// ---------------------------------------------------------------------------
// scores = Q K^T / 32 : 256x256 tiles, grid 256 = 8(N)*8(M)*4(b)
// ---------------------------------------------------------------------------
__global__ __launch_bounds__(512, 2) void gemm_scores(
    const uint16_t* __restrict__ Qh, const uint16_t* __restrict__ Kh, float* __restrict__ C)
{
    __shared__ __align__(16) uint8_t smem[131072];
    const int f = blockIdx.x;
    const int swz = (f & 7) * 32 + (f >> 3);      // 256 = 8*32
    const int z = swz >> 6;
    const int rm = swz & 63;
    const int tileM = (rm >> 3) * 256, tileN = (rm & 7) * 256;

    f32x4 acc[8][4];
#pragma unroll
    for (int i = 0; i < 8; ++i)
#pragma unroll
        for (int j = 0; j < 4; ++j) acc[i][j] = (f32x4){0.f, 0.f, 0.f, 0.f};

    gemm_core256<256>(Qh + (size_t)z * S_ * K3, Kh + (size_t)z * S_ * K3, K3,
                      tileM, tileN, smem, acc);

    float* Cb = C + (size_t)z * S_ * S_;
    const int lane = threadIdx.x & 63, wave = threadIdx.x >> 6;
    const int waveM = wave >> 2, waveN = wave & 3;
#pragma unroll
    for (int i = 0; i < 8; ++i)
#pragma unroll
        for (int j = 0; j < 4; ++j) {
            int col = tileN + waveN * 64 + j * 16 + (lane & 15);
#pragma unroll
            for (int r = 0; r < 4; ++r) {
                int row = tileM + waveM * 128 + i * 16 + (lane >> 4) * 4 + r;
                Cb[(size_t)row * S_ + col] = acc[i][j][r] * (1.0f / 32.0f);
            }
        }
}

// ---------------------------------------------------------------------------
// context = P V : 128x256 tiles (fills 256 CUs), grid 256 = 4(N)*16(M)*4(b)
// ---------------------------------------------------------------------------
__global__ __launch_bounds__(512, 2) void gemm_pv(
    const uint16_t* __restrict__ Ph, const uint16_t* __restrict__ Vt, float* __restrict__ C)
{
    __shared__ __align__(16) uint8_t smem[98304];
    const int f = blockIdx.x;
    const int swz = (f & 7) * 32 + (f >> 3);      // 256 = 8*32
    const int z = swz >> 6;
    const int rm = swz & 63;
    const int tileM = (rm >> 2) * 128, tileN = (rm & 3) * 256;

    f32x4 acc[4][4];
#pragma unroll
    for (int i = 0; i < 4; ++i)
#pragma unroll
        for (int j = 0; j < 4; ++j) acc[i][j] = (f32x4){0.f, 0.f, 0.f, 0.f};

    gemm_core256<128>(Ph + (size_t)z * S_ * K6, Vt + (size_t)z * E_ * K6, K6,
                      tileM, tileN, smem, acc);

    float* Cb = C + (size_t)z * S_ * E_;
    const int lane = threadIdx.x & 63, wave = threadIdx.x >> 6;
    const int waveM = wave >> 2, waveN = wave & 3;
#pragma unroll
    for (int i = 0; i < 4; ++i)
#pragma unroll
        for (int j = 0; j < 4; ++j) {
            int col = tileN + waveN * 64 + j * 16 + (lane & 15);
#pragma unroll
            for (int r = 0; r < 4; ++r) {
                int row = tileM + waveM * 64 + i * 16 + (lane >> 4) * 4 + r;
                Cb[(size_t)row * E_ + col] = acc[i][j][r];
            }
        }
}

// ---------------------------------------------------------------------------
// V transpose: Vhi/Vlo [b][t][e] -> Vt [b][e][3T] pattern [hi | lo | hi]
// ---------------------------------------------------------------------------
__global__ void transpose_v(const uint16_t* __restrict__ Vhi, const uint16_t* __restrict__ Vlo,
                            uint16_t* __restrict__ Vt)
{
    __shared__ uint16_t sh[32][33];
    __shared__ uint16_t sl[32][33];
    const int b = blockIdx.z;
    const int t0 = blockIdx.x * 32, e0 = blockIdx.y * 32;
    const int tx = threadIdx.x & 31, ty = threadIdx.x >> 5;
    for (int r = ty; r < 32; r += 8) {
        size_t src = ((size_t)b * S_ + t0 + r) * E_ + e0 + tx;
        sh[r][tx] = Vhi[src];
        sl[r][tx] = Vlo[src];
    }
    __syncthreads();
    for (int r = ty; r < 32; r += 8) {
        size_t base = ((size_t)b * E_ + e0 + r) * (size_t)K6;
        uint16_t h = sh[tx][r], l = sl[tx][r];
        Vt[base + t0 + tx] = h;
        Vt[base + S_ + t0 + tx] = l;
        Vt[base + 2 * S_ + t0 + tx] = h;
    }
}

// ---------------------------------------------------------------------------
// masked softmax over one score row + split-pack P: Phat [hi | hi | lo] over t
// ---------------------------------------------------------------------------
__global__ __launch_bounds__(256) void softmax_split(const float* __restrict__ scores,
                                                     const int* __restrict__ buckets,
                                                     uint16_t* __restrict__ Phat)
{
    const int s = blockIdx.x, b = blockIdx.y;
    const float* row = scores + ((size_t)b * S_ + s) * S_;
    const int* brow = buckets + b * S_;
    const int myb = brow[s];
    const int tid = threadIdx.x;
    const int lane = tid & 63, wave = tid >> 6;

    float vals[8];
    float m = -1e30f;
#pragma unroll
    for (int i = 0; i < 8; ++i) {
        int t = tid + i * 256;
        float x = row[t];
        x = (brow[t] == myb) ? x : -1e30f;
        vals[i] = x;
        m = fmaxf(m, x);
    }
#pragma unroll
    for (int off = 32; off > 0; off >>= 1) m = fmaxf(m, __shfl_xor(m, off));
    __shared__ float red[8];
    if (lane == 0) red[wave] = m;
    __syncthreads();
    m = fmaxf(fmaxf(red[0], red[1]), fmaxf(red[2], red[3]));

    float sum = 0.f;
#pragma unroll
    for (int i = 0; i < 8; ++i) {
        float p = __expf(vals[i] - m);
        vals[i] = p;
        sum += p;
    }
#pragma unroll
    for (int off = 32; off > 0; off >>= 1) sum += __shfl_xor(sum, off);
    if (lane == 0) red[4 + wave] = sum;
    __syncthreads();
    sum = red[4] + red[5] + red[6] + red[7];
    float inv = 1.f / sum;

    size_t base = ((size_t)b * S_ + s) * (size_t)K6;
#pragma unroll
    for (int i = 0; i < 8; ++i) {
        int t = tid + i * 256;
        float p = vals[i] * inv;
        uint16_t hi = f2bf(p);
        uint16_t lo = f2bf(p - bf2f(hi));
        Phat[base + t] = hi;
        Phat[base + S_ + t] = hi;
        Phat[base + 2 * S_ + t] = lo;
    }
}

// ---------------------------------------------------------------------------
extern "C" void kernel_launch(void* const* d_in, const int* in_sizes, int n_in,
                              void* d_out, int out_size, void* d_ws, size_t ws_size,
                              hipStream_t stream)
{
    const float* h  = (const float*)d_in[0];
    const int*   hb = (const int*)d_in[1];
    const float* Wq = (const float*)d_in[2];
    const float* bq = (const float*)d_in[3];
    const float* Wk = (const float*)d_in[4];
    const float* bk = (const float*)d_in[5];
    const float* Wv = (const float*)d_in[6];
    const float* bv = (const float*)d_in[7];
    float* out = (float*)d_out;
    uint8_t* ws = (uint8_t*)d_ws;

    uint16_t* Hhat = (uint16_t*)(ws + OFF_HHAT);
    uint16_t* What = (uint16_t*)(ws + OFF_WHAT);
    uint16_t* Qhat = (uint16_t*)(ws + OFF_QHAT);
    uint16_t* Khat = (uint16_t*)(ws + OFF_KHAT);
    uint16_t* Vt   = (uint16_t*)(ws + OFF_VT);
    uint16_t* Vhi  = (uint16_t*)(ws + OFF_VHI);
    uint16_t* Vlo  = (uint16_t*)(ws + OFF_VLO);
    float*    sc   = (float*)(ws + OFF_SC);
    uint16_t* Phat = (uint16_t*)(ws + OFF_PHAT);

    pack_inputs<<<dim3(11264), 256, 0, stream>>>(h, Wq, Wk, Wv, Hhat, What);
    gemm_proj2<<<dim3(384), 512, 0, stream>>>(Hhat, What, bq, bk, bv, Qhat, Khat, Vhi, Vlo);
    transpose_v<<<dim3(64, 32, 4), 256, 0, stream>>>(Vhi, Vlo, Vt);
    gemm_scores<<<dim3(256), 512, 0, stream>>>(Qhat, Khat, sc);
    softmax_split<<<dim3(S_, B_), 256, 0, stream>>>(sc, hb, Phat);
    gemm_pv<<<dim3(256), 512, 0, stream>>>(Phat, Vt, out);
}